// Round 2
// baseline (887.785 us; speedup 1.0000x reference)
//
#include <hip/hip_runtime.h>
#include <cmath>
#include <cstdint>

// B=2, L=2048, DIM=1024, NH=16, HD=64
typedef _Float16 half8 __attribute__((ext_vector_type(8)));
typedef _Float16 half4 __attribute__((ext_vector_type(4)));
typedef float f32x4 __attribute__((ext_vector_type(4)));

#define NEGBIG (-3.4028235e38f)

// async global->LDS, 16B per lane. lds ptr passed per-lane but HW uses
// wave-uniform base + lane*16; our slot mapping satisfies exactly that.
__device__ __forceinline__ void async16(const void* g, void* l) {
    __builtin_amdgcn_global_load_lds(
        (const __attribute__((address_space(1))) uint32_t*)g,
        (__attribute__((address_space(3))) uint32_t*)l, 16, 0, 0);
}

// ---------------- cast x: f32 -> f16 ----------------
__global__ void cast4_kernel(const float* __restrict__ in, _Float16* __restrict__ out, int n) {
    int i = (blockIdx.x * 256 + threadIdx.x) * 4;
    if (i < n) {
        float4 v = *(const float4*)&in[i];
        half4 o = { (_Float16)v.x, (_Float16)v.y, (_Float16)v.z, (_Float16)v.w };
        *(half4*)&out[i] = o;
    }
}

// ---------------- transpose+cast weight: W[k][n] f32 -> Wt[n][k] f16 ----------------
__global__ void transpose_cast_kernel(const float* __restrict__ W, _Float16* __restrict__ Wt) {
    __shared__ float tile[32][33];
    int bx = blockIdx.x * 32;  // k base
    int by = blockIdx.y * 32;  // n base
    int tx = threadIdx.x & 31, ty = threadIdx.x >> 5;  // ty 0..7
    #pragma unroll
    for (int r = 0; r < 32; r += 8)
        tile[ty + r][tx] = W[(size_t)(bx + ty + r) * 1024 + by + tx];
    __syncthreads();
    #pragma unroll
    for (int r = 0; r < 32; r += 8)
        Wt[(size_t)(by + ty + r) * 1024 + bx + tx] = (_Float16)tile[tx][ty + r];
}

// ---------------- fused QKV GEMM (m97-style): X[4096][1024] @ Wt -> Q/K [b,h,l,d], V^T [b,h,d,l] ----------------
__global__ __launch_bounds__(256)
void gemm_qkv_kernel(const _Float16* __restrict__ X,
                     const _Float16* __restrict__ WqT, const _Float16* __restrict__ WkT,
                     const _Float16* __restrict__ WvT,
                     _Float16* __restrict__ Qh, _Float16* __restrict__ Kh, _Float16* __restrict__ VTh)
{
    __shared__ __align__(16) char smem_raw[34816];   // max(A+B staging 32KB, Ct 128*136*2)
    _Float16* Alds = (_Float16*)smem_raw;            // [128][64] unpadded (global_load_lds)
    _Float16* Blds = Alds + 8192;                    // [128][64]
    typedef _Float16 CtRow[136];                     // 136*2=272B rows: 16B aligned
    CtRow* Ct = (CtRow*)smem_raw;

    const int z = blockIdx.z;
    const _Float16* __restrict__ Bt = (z == 0) ? WqT : (z == 1) ? WkT : WvT;

    const int tid = threadIdx.x;
    const int bm = blockIdx.x * 128, bn = blockIdx.y * 128;
    const int wave = tid >> 6, lane = tid & 63;
    const int wm = (wave >> 1) * 64, wn = (wave & 1) * 64;
    const int quad = lane >> 4, l16 = lane & 15;

    f32x4 acc[4][4] = {};

    for (int k0 = 0; k0 < 1024; k0 += 64) {
        #pragma unroll
        for (int t = 0; t < 4; ++t) {
            int s = t * 256 + tid;              // slot 0..1023; 8 slots (16B) per 64-half row
            int row = s >> 3, kc = (s & 7) * 8;
            async16(&X [(size_t)(bm + row) * 1024 + k0 + kc], &Alds[s * 8]);
            async16(&Bt[(size_t)(bn + row) * 1024 + k0 + kc], &Blds[s * 8]);
        }
        __syncthreads();   // drains vmcnt (async) per barrier semantics
        #pragma unroll
        for (int kk = 0; kk < 64; kk += 32) {
            half8 af[4], bf[4];
            #pragma unroll
            for (int mt = 0; mt < 4; ++mt) af[mt] = *(const half8*)&Alds[(wm + mt*16 + l16) * 64 + kk + quad * 8];
            #pragma unroll
            for (int nt = 0; nt < 4; ++nt) bf[nt] = *(const half8*)&Blds[(wn + nt*16 + l16) * 64 + kk + quad * 8];
            #pragma unroll
            for (int mt = 0; mt < 4; ++mt)
                #pragma unroll
                for (int nt = 0; nt < 4; ++nt)
                    acc[mt][nt] = __builtin_amdgcn_mfma_f32_16x16x32_f16(af[mt], bf[nt], acc[mt][nt], 0, 0, 0);
        }
        __syncthreads();
    }

    // epilogue via LDS: normal orientation for Q/K, transposed for V (so stores coalesce)
    #pragma unroll
    for (int mt = 0; mt < 4; ++mt)
        #pragma unroll
        for (int nt = 0; nt < 4; ++nt)
            #pragma unroll
            for (int r = 0; r < 4; ++r) {
                int row = wm + mt * 16 + quad * 4 + r;    // m within tile
                int col = wn + nt * 16 + l16;             // n within tile
                _Float16 hv = (_Float16)acc[mt][nt][r];
                if (z < 2) Ct[row][col] = hv; else Ct[col][row] = hv;
            }
    __syncthreads();

    const int bb = bm >> 11, lbase = bm & 2047;
    _Float16* __restrict__ outQK = (z == 0) ? Qh : Kh;
    #pragma unroll
    for (int step = 0; step < 8; ++step) {
        int r  = step * 16 + (tid >> 4);
        int c8 = (tid & 15) * 8;
        half8 v = *(const half8*)&Ct[r][c8];
        if (z < 2) {
            int n = bn + c8, hh = n >> 6, dd = n & 63;
            *(half8*)&outQK[(((size_t)(bb * 16 + hh)) * 2048 + (lbase + r)) * 64 + dd] = v;
        } else {
            int n = bn + r, hh = n >> 6, dd = n & 63;
            *(half8*)&VTh[(((size_t)(bb * 16 + hh)) * 64 + dd) * 2048 + lbase + c8] = v;
        }
    }
}

// ---------------- flash attention with additive bias + key mask ----------------
__device__ __forceinline__ float rowmax16(float v) {
    #pragma unroll
    for (int off = 1; off < 16; off <<= 1) v = fmaxf(v, __shfl_xor(v, off));
    return v;
}
__device__ __forceinline__ float rowsum16(float v) {
    #pragma unroll
    for (int off = 1; off < 16; off <<= 1) v += __shfl_xor(v, off);
    return v;
}

__global__ __launch_bounds__(256)
void flash_attn_kernel(const _Float16* __restrict__ Qh, const _Float16* __restrict__ Kh,
                       const _Float16* __restrict__ VTh, const float* __restrict__ bias,
                       const int* __restrict__ mask, _Float16* __restrict__ AO)
{
    const int qt = blockIdx.x, h = blockIdx.y, b = blockIdx.z;
    const int tid = threadIdx.x, wave = tid >> 6, lane = tid & 63;
    const int quad = lane >> 4, l16 = lane & 15;

    __shared__ __align__(16) _Float16 Kt[64 * 64];   // [j][d] unpadded (async staging)
    __shared__ __align__(16) _Float16 Vt[64 * 64];   // [d][j] unpadded (async staging)
    __shared__ _Float16 Pw[4][16][72];               // per-wave P
    __shared__ float    Bs[64][66];                  // bias tile (masked), pad 66: conflict-free reads

    const size_t head = (size_t)(b * 16 + h) * 2048 * 64;
    const int i_base = qt * 64 + wave * 16;
    const size_t bias_base = ((size_t)((b * 16 + h) * 2048 + qt * 64)) * 2048;

    half8 qf0 = *(const half8*)&Qh[head + (size_t)(i_base + l16) * 64 + quad * 8];
    half8 qf1 = *(const half8*)&Qh[head + (size_t)(i_base + l16) * 64 + 32 + quad * 8];

    float m_r[4] = { -INFINITY, -INFINITY, -INFINITY, -INFINITY };
    float l_r[4] = {};
    f32x4 o[4] = {};

    // register-prefetched bias + mask (one j-tile ahead)
    float4 bpre[4]; int4 mpre[4];
    #pragma unroll
    for (int p = 0; p < 4; ++p) {
        int s = p * 256 + tid; int il = s >> 4; int jc = (s & 15) * 4;
        bpre[p] = *(const float4*)&bias[bias_base + (size_t)il * 2048 + jc];
        mpre[p] = *(const int4*)&mask[b * 2048 + jc];
    }

    for (int j0 = 0; j0 < 2048; j0 += 64) {
        // async K/V tile staging
        #pragma unroll
        for (int c = 0; c < 2; ++c) {
            int s = c * 256 + tid;              // 512 slots; 8 slots per 64-half row
            int row = s >> 3, dc = (s & 7) * 8;
            async16(&Kh [head + (size_t)(j0 + row) * 64 + dc], &Kt[s * 8]);
            async16(&VTh[head + (size_t)row * 2048 + j0 + dc], &Vt[s * 8]);
        }
        // masked bias tile -> LDS from prefetch regs
        #pragma unroll
        for (int p = 0; p < 4; ++p) {
            int s = p * 256 + tid; int il = s >> 4; int jc = (s & 15) * 4;
            float4 v = bpre[p]; int4 mv = mpre[p];
            Bs[il][jc + 0] = mv.x ? v.x : NEGBIG;
            Bs[il][jc + 1] = mv.y ? v.y : NEGBIG;
            Bs[il][jc + 2] = mv.z ? v.z : NEGBIG;
            Bs[il][jc + 3] = mv.w ? v.w : NEGBIG;
        }
        __syncthreads();

        // prefetch next bias tile (lands during compute)
        if (j0 + 64 < 2048) {
            #pragma unroll
            for (int p = 0; p < 4; ++p) {
                int s = p * 256 + tid; int il = s >> 4; int jc = (s & 15) * 4;
                bpre[p] = *(const float4*)&bias[bias_base + (size_t)il * 2048 + j0 + 64 + jc];
                mpre[p] = *(const int4*)&mask[b * 2048 + j0 + 64 + jc];
            }
        }

        float sreg[4][4];
        #pragma unroll
        for (int jt = 0; jt < 4; ++jt) {
            half8 kf0 = *(const half8*)&Kt[(jt * 16 + l16) * 64 + quad * 8];
            half8 kf1 = *(const half8*)&Kt[(jt * 16 + l16) * 64 + 32 + quad * 8];
            f32x4 s = {};
            s = __builtin_amdgcn_mfma_f32_16x16x32_f16(qf0, kf0, s, 0, 0, 0);
            s = __builtin_amdgcn_mfma_f32_16x16x32_f16(qf1, kf1, s, 0, 0, 0);
            #pragma unroll
            for (int r = 0; r < 4; ++r)
                sreg[jt][r] = s[r] + Bs[wave * 16 + quad * 4 + r][jt * 16 + l16];
        }

        float alpha[4];
        #pragma unroll
        for (int r = 0; r < 4; ++r) {
            float mx = fmaxf(fmaxf(sreg[0][r], sreg[1][r]), fmaxf(sreg[2][r], sreg[3][r]));
            mx = rowmax16(mx);
            float mnew = fmaxf(m_r[r], mx);
            alpha[r] = __expf(m_r[r] - mnew);
            m_r[r] = mnew;
            float ps = 0.f;
            #pragma unroll
            for (int jt = 0; jt < 4; ++jt) {
                float p = __expf(sreg[jt][r] - mnew);
                Pw[wave][quad * 4 + r][jt * 16 + l16] = (_Float16)p;
                ps += p;
            }
            ps = rowsum16(ps);
            l_r[r] = l_r[r] * alpha[r] + ps;
        }
        #pragma unroll
        for (int nt = 0; nt < 4; ++nt)
            #pragma unroll
            for (int r = 0; r < 4; ++r)
                o[nt][r] *= alpha[r];

        half8 pf0 = *(const half8*)&Pw[wave][l16][quad * 8];
        half8 pf1 = *(const half8*)&Pw[wave][l16][32 + quad * 8];
        #pragma unroll
        for (int nt = 0; nt < 4; ++nt) {
            half8 vf0 = *(const half8*)&Vt[(nt * 16 + l16) * 64 + quad * 8];
            half8 vf1 = *(const half8*)&Vt[(nt * 16 + l16) * 64 + 32 + quad * 8];
            o[nt] = __builtin_amdgcn_mfma_f32_16x16x32_f16(pf0, vf0, o[nt], 0, 0, 0);
            o[nt] = __builtin_amdgcn_mfma_f32_16x16x32_f16(pf1, vf1, o[nt], 0, 0, 0);
        }
        __syncthreads();
    }

    #pragma unroll
    for (int nt = 0; nt < 4; ++nt) {
        #pragma unroll
        for (int r = 0; r < 4; ++r) {
            float val = o[nt][r] / l_r[r];
            AO[(size_t)(b * 2048 + i_base + quad * 4 + r) * 1024 + h * 64 + nt * 16 + l16] = (_Float16)val;
        }
    }
}

// ---------------- output projection (m97-style): AO[4096][1024] @ woT -> f32 out ----------------
__global__ __launch_bounds__(256)
void gemm_out_kernel(const _Float16* __restrict__ A, const _Float16* __restrict__ Bt,
                     float* __restrict__ C)
{
    __shared__ __align__(16) _Float16 Alds[8192];   // [128][64] unpadded
    __shared__ __align__(16) _Float16 Blds[8192];

    const int tid = threadIdx.x;
    const int bm = blockIdx.x * 128, bn = blockIdx.y * 128;
    const int wave = tid >> 6, lane = tid & 63;
    const int wm = (wave >> 1) * 64, wn = (wave & 1) * 64;
    const int quad = lane >> 4, l16 = lane & 15;

    f32x4 acc[4][4] = {};

    for (int k0 = 0; k0 < 1024; k0 += 64) {
        #pragma unroll
        for (int t = 0; t < 4; ++t) {
            int s = t * 256 + tid;
            int row = s >> 3, kc = (s & 7) * 8;
            async16(&A [(size_t)(bm + row) * 1024 + k0 + kc], &Alds[s * 8]);
            async16(&Bt[(size_t)(bn + row) * 1024 + k0 + kc], &Blds[s * 8]);
        }
        __syncthreads();
        #pragma unroll
        for (int kk = 0; kk < 64; kk += 32) {
            half8 af[4], bf[4];
            #pragma unroll
            for (int mt = 0; mt < 4; ++mt) af[mt] = *(const half8*)&Alds[(wm + mt*16 + l16) * 64 + kk + quad * 8];
            #pragma unroll
            for (int nt = 0; nt < 4; ++nt) bf[nt] = *(const half8*)&Blds[(wn + nt*16 + l16) * 64 + kk + quad * 8];
            #pragma unroll
            for (int mt = 0; mt < 4; ++mt)
                #pragma unroll
                for (int nt = 0; nt < 4; ++nt)
                    acc[mt][nt] = __builtin_amdgcn_mfma_f32_16x16x32_f16(af[mt], bf[nt], acc[mt][nt], 0, 0, 0);
        }
        __syncthreads();
    }

    #pragma unroll
    for (int mt = 0; mt < 4; ++mt)
        #pragma unroll
        for (int nt = 0; nt < 4; ++nt)
            #pragma unroll
            for (int r = 0; r < 4; ++r) {
                int m = bm + wm + mt * 16 + quad * 4 + r;
                int n = bn + wn + nt * 16 + l16;
                C[(size_t)m * 1024 + n] = acc[mt][nt][r];
            }
}

extern "C" void kernel_launch(void* const* d_in, const int* in_sizes, int n_in,
                              void* d_out, int out_size, void* d_ws, size_t ws_size,
                              hipStream_t stream)
{
    const float* x    = (const float*)d_in[0];
    const float* bias = (const float*)d_in[1];
    const int*   mask = (const int*)d_in[2];
    const float* wq   = (const float*)d_in[3];
    const float* wk   = (const float*)d_in[4];
    const float* wv   = (const float*)d_in[5];
    const float* wo   = (const float*)d_in[6];
    float* out = (float*)d_out;

    char* ws = (char*)d_ws;
    const size_t MB = 1024 * 1024;
    _Float16* x_h = (_Float16*)(ws + 0);        // 8 MB; reused as AO after QKV GEMMs
    _Float16* AO  = x_h;
    _Float16* wqT = (_Float16*)(ws + 8 * MB);
    _Float16* wkT = (_Float16*)(ws + 10 * MB);
    _Float16* wvT = (_Float16*)(ws + 12 * MB);
    _Float16* woT = (_Float16*)(ws + 14 * MB);
    _Float16* Qh  = (_Float16*)(ws + 16 * MB);  // [b][h][l][d]
    _Float16* Kh  = (_Float16*)(ws + 24 * MB);  // [b][h][l][d]
    _Float16* VTh = (_Float16*)(ws + 32 * MB);  // [b][h][d][l]

    cast4_kernel<<<4096, 256, 0, stream>>>(x, x_h, 4096 * 1024);
    dim3 tg(32, 32);
    transpose_cast_kernel<<<tg, 256, 0, stream>>>(wq, wqT);
    transpose_cast_kernel<<<tg, 256, 0, stream>>>(wk, wkT);
    transpose_cast_kernel<<<tg, 256, 0, stream>>>(wv, wvT);
    transpose_cast_kernel<<<tg, 256, 0, stream>>>(wo, woT);

    gemm_qkv_kernel<<<dim3(32, 8, 3), 256, 0, stream>>>(x_h, wqT, wkT, wvT, Qh, Kh, VTh);
    flash_attn_kernel<<<dim3(32, 16, 2), 256, 0, stream>>>(Qh, Kh, VTh, bias, mask, AO);
    gemm_out_kernel<<<dim3(32, 8), 256, 0, stream>>>(AO, woT, out);
}